// Round 8
// baseline (154.337 us; speedup 1.0000x reference)
//
#include <hip/hip_runtime.h>
#include <math.h>

#define BATCH 4
#define CH    256   // feature channels == depth of sampled volume
#define HH    128
#define WW    128
#define PC    256   // para channels
#define PI_F  3.14159f
#define PLANE (HH * WW)   // 16384 floats
#define NP    2           // planes per block (grid = 512 -> 2 blocks/CU)

// Padded LDS plane: rows -1..129 (index y+1 in [0,130]), cols -1..132.
// Stride 134 (mod 32 = 6): any linear lane-walk hits >=16 banks => <=2-way
// conflict = free. Border cells hold 0.0f => padding_mode='zeros' free.
#define PSTRIDE 134
#define PROWS   131
#define BUFSZ   (PROWS * PSTRIDE)   // 17554 words = 70216 B

// Light barrier: drains LDS ops only (lgkmcnt), NOT vmcnt — global loads and
// output stores stay in flight across it. All cross-wave hazards here are
// LDS-only.
__device__ __forceinline__ void barrier_lds() {
    asm volatile("s_waitcnt lgkmcnt(0)\n\ts_barrier" ::: "memory");
}

struct Stage { float4 a[4]; float4 b[4]; };

__device__ __forceinline__ Stage stage_load(const float* __restrict__ pl0,
                                            const float* __restrict__ pl1, int t) {
    Stage s;
#pragma unroll
    for (int j = 0; j < 4; ++j) {
        const int f = 4 * (t + 1024 * j);
        s.a[j] = *(const float4*)(pl0 + f);
        s.b[j] = *(const float4*)(pl1 + f);
    }
    return s;
}

// z-combine + scatter into padded layout (interior cells only).
__device__ __forceinline__ void stage_store_pad(float* __restrict__ buf, const Stage& s,
                                                float wz0, float wz1, int t) {
#pragma unroll
    for (int j = 0; j < 4; ++j) {
        const int f = 4 * (t + 1024 * j);
        const int y = f >> 7, x = f & (WW - 1);
        float* p = &buf[(y + 1) * PSTRIDE + (x + 1)];
        p[0] = fmaf(wz0, s.a[j].x, wz1 * s.b[j].x);
        p[1] = fmaf(wz0, s.a[j].y, wz1 * s.b[j].y);
        p[2] = fmaf(wz0, s.a[j].z, wz1 * s.b[j].z);
        p[3] = fmaf(wz0, s.a[j].w, wz1 * s.b[j].w);
    }
}

// Bilinear gather from padded plane; P.z/P.w carry the +1 border bias.
// Clamp into [0,129.99]: OOB pixels read stored zeros (exact zero-padding).
__device__ __forceinline__ void gather_plane(const float* __restrict__ buf,
                                             const float4 P,
                                             float* __restrict__ outp,
                                             const float yf, const int xi) {
    const float cA  = P.x, cB = P.y;
    float ixp = fmaf(cA, (float)xi, fmaf(-cB, yf, P.z));
    float iyp = fmaf(cB, (float)xi, fmaf( cA, yf, P.w));
    const float dx8 = 8.0f * cA, dy8 = 8.0f * cB;
#pragma unroll 4
    for (int k = 0; k < 16; ++k) {
        const float xc  = fminf(fmaxf(ixp, 0.0f), 129.99f);
        const float yc  = fminf(fmaxf(iyp, 0.0f), 129.99f);
        const float x0f = floorf(xc), y0f = floorf(yc);
        const float fx  = xc - x0f,   fy  = yc - y0f;
        const int   a   = (int)y0f * PSTRIDE + (int)x0f;
        const float v00 = buf[a],           v01 = buf[a + 1];           // ds_read2
        const float v10 = buf[a + PSTRIDE], v11 = buf[a + PSTRIDE + 1]; // ds_read2
        const float h0  = fmaf(fx, v01 - v00, v00);
        const float h1  = fmaf(fx, v11 - v10, v10);
        outp[k * 8 + xi] = fmaf(fy, h1 - h0, h0);
        ixp += dx8; iyp += dy8;
    }
}

// ---------------------------------------------------------------------------
// One launch, 512 blocks x 1024 threads, NP=2 planes/block, single padded
// buffer (70 KB) -> 2 blocks/CU, 32 waves/CU. Co-resident block fills every
// vmcnt / barrier stall (cross-block pipelining instead of double-buffer).
// ---------------------------------------------------------------------------
__global__ __launch_bounds__(1024, 8)
void adaat_fused_kernel(const float* __restrict__ fm,
                        const float* __restrict__ pc,
                        const float* __restrict__ W1, const float* __restrict__ b1,
                        const float* __restrict__ Ws, const float* __restrict__ bs,
                        const float* __restrict__ Wr, const float* __restrict__ br,
                        const float* __restrict__ Wt, const float* __restrict__ bt,
                        float* __restrict__ out) {
    __shared__ float  lds[BUFSZ];       // 70.2 KiB padded plane buffer
    __shared__ float  red[1024];        // GEMV reduce scratch
    __shared__ float  p_sh[PC];
    __shared__ float  sh_head[8];       // NP*4
    __shared__ float4 sh_par[NP];

    const int t   = threadIdx.x;
    const int bc0 = blockIdx.x * NP;    // NP | 256 so no batch straddle
    const int b   = bc0 >> 8;

    // block-uniform staging constants (scalarized)
    const float* base = fm + (size_t)b * (CH * PLANE);
    const float* pl0[NP]; const float* pl1[NP];
    float w0[NP], w1[NP];
#pragma unroll
    for (int i = 0; i < NP; ++i) {
        const int   c  = (bc0 + i) & (CH - 1);
        const float iz = (256.0f / 255.0f) * (float)c - 0.5f;
        const float zf = floorf(iz);
        const float fz = iz - zf;
        const int   z0 = (int)zf;
        w0[i]  = (z0 >= 0)     ? (1.0f - fz) : 0.0f;
        w1[i]  = (z0 + 1 < CH) ? fz          : 0.0f;
        pl0[i] = base + (size_t)max(z0, 0)          * PLANE;
        pl1[i] = base + (size_t)min(z0 + 1, CH - 1) * PLANE;
    }

    // ---- 1) plane-0 staging loads in flight through the params phase ----
    Stage s = stage_load(pl0[0], pl1[0], t);

    // ---- 2) zero the padded buffer (borders must read 0.0f) ----
#pragma unroll
    for (int i = 0; i < 18; ++i) {
        const int idx = t + 1024 * i;
        if (idx < BUFSZ) lds[idx] = 0.0f;
    }

    // ---- 3) p = relu(pc @ W1 + b1), 4-way k-split ----
    {
        const int jj = t & 255, kk = t >> 8;
        const float* pcb = pc + b * PC + kk * 64;
        const float* w   = W1 + (kk * 64) * PC + jj;
        float acc = 0.0f;
#pragma unroll 8
        for (int i = 0; i < 64; ++i)
            acc = fmaf(pcb[i], w[i * PC], acc);
        red[t] = acc;
    }
    barrier_lds();
    if (t < 256)
        p_sh[t] = fmaxf(red[t] + red[256 + t] + red[512 + t] + red[768 + t] + b1[t], 0.0f);
    barrier_lds();   // p_sh visible; zeroing drained

    // ---- 4) store plane 0 (waits its own vmcnt only); frees Stage regs ----
    stage_store_pad(lds, s, w0[0], w1[0], t);

    // ---- 5) head dots: wave wv -> channel q = wv>>2 (<NP), head wv&3 ----
    const int wv = t >> 6, l = t & 63;
    if (wv < 4 * NP) {
        const int q  = wv >> 2;
        const int h  = wv & 3;
        const int cq = (bc0 + q) & (CH - 1);
        const float* wp; int stride;
        if      (h == 0) { wp = Ws + cq;                stride = PC;     }
        else if (h == 1) { wp = Wr + cq;                stride = PC;     }
        else             { wp = Wt + 2 * cq + (h == 3); stride = 2 * PC; }
        float dot = 0.0f;
#pragma unroll
        for (int m = 0; m < 4; ++m) {
            const int k = l + 64 * m;
            dot = fmaf(p_sh[k], wp[(size_t)k * stride], dot);
        }
#pragma unroll
        for (int off = 32; off >= 1; off >>= 1)
            dot += __shfl_xor(dot, off, 64);
        if (l == 0) sh_head[wv] = dot;
    }
    barrier_lds();

    // ---- 6) transcendentals -> fused padded-pixel-space constants ----
    if (t < NP) {
        const int cq = (bc0 + t) & (CH - 1);
        const float s2  = 2.0f / (1.0f + expf(-(sh_head[4 * t] + bs[cq])));
        const float ang = tanhf(sh_head[4 * t + 1] + br[cq]) * PI_F;
        float sa, ca;
        sincosf(ang, &sa, &ca);
        const float A  = s2 * ca, B = s2 * sa;
        const float Tx = tanhf(sh_head[4 * t + 2] + bt[2 * cq]);
        const float Ty = tanhf(sh_head[4 * t + 3] + bt[2 * cq + 1]);
        sh_par[t] = make_float4(A * (128.0f / 127.0f),
                                B * (128.0f / 127.0f),
                                64.0f * (Tx - A + B) + 64.5f,   // +1 border bias
                                64.0f * (Ty - A - B) + 64.5f);
    }
    barrier_lds();   // sh_par + plane-0 stores visible

    // ---- 7) pipeline over NP=2 planes, single buffer ----
    const int   xi = l & 7;                 // wave = 8x8 pixel tile
    const int   yj = wv * 8 + (l >> 3);
    const float yf = (float)yj;

    s = stage_load(pl0[1], pl1[1], t);      // in flight during gather(0)
    gather_plane(lds, sh_par[0],
                 out + (size_t)bc0 * PLANE + yj * WW, yf, xi);
    barrier_lds();                          // WAR: all gathers done
    stage_store_pad(lds, s, w0[1], w1[1], t);
    barrier_lds();                          // RAW: stores visible
    gather_plane(lds, sh_par[1],
                 out + (size_t)(bc0 + 1) * PLANE + yj * WW, yf, xi);
}

// ---------------------------------------------------------------------------
extern "C" void kernel_launch(void* const* d_in, const int* in_sizes, int n_in,
                              void* d_out, int out_size, void* d_ws, size_t ws_size,
                              hipStream_t stream) {
    const float* feature_map = (const float*)d_in[0];  // [4,256,128,128]
    const float* para_code   = (const float*)d_in[1];  // [4,256]
    const float* W1 = (const float*)d_in[2];
    const float* b1 = (const float*)d_in[3];
    const float* Ws = (const float*)d_in[4];
    const float* bs = (const float*)d_in[5];
    const float* Wr = (const float*)d_in[6];
    const float* br = (const float*)d_in[7];
    const float* Wt = (const float*)d_in[8];
    const float* bt = (const float*)d_in[9];

    adaat_fused_kernel<<<BATCH * CH / NP, 1024, 0, stream>>>(
        feature_map, para_code, W1, b1, Ws, bs, Wr, br, Wt, bt, (float*)d_out);
}

// Round 9
// 152.722 us; speedup vs baseline: 1.0106x; 1.0106x over previous
//
#include <hip/hip_runtime.h>
#include <math.h>

#define BATCH 4
#define CH    256   // feature channels == depth of sampled volume
#define HH    128
#define WW    128
#define PC    256   // para channels
#define PI_F  3.14159f
#define PLANE (HH * WW)   // 16384 floats
#define NP    4           // planes per block (grid = 256 -> 1 block/CU)

// Padded LDS plane: rows -1..129 (index y+1 in [0,130]), cols -1..132.
// Stride 134 (mod 32 = 6): linear lane-walks hit >=16 banks => ~2-way
// conflict = free. Border cells hold 0.0f => padding_mode='zeros' free.
#define PSTRIDE 134
#define PROWS   131
#define BUFSZ   (PROWS * PSTRIDE)   // 17554 words = 70216 B

// Light barrier: drains LDS ops only (lgkmcnt), NOT vmcnt — global loads and
// output stores stay in flight across it. All cross-wave hazards here are
// LDS-only (double buffer handles WAR/RAW on plane buffers).
__device__ __forceinline__ void barrier_lds() {
    asm volatile("s_waitcnt lgkmcnt(0)\n\ts_barrier" ::: "memory");
}

struct Stage { float4 a[4]; float4 b[4]; };   // 32 VGPRs

__device__ __forceinline__ Stage stage_load(const float* __restrict__ pl0,
                                            const float* __restrict__ pl1, int t) {
    Stage s;
#pragma unroll
    for (int j = 0; j < 4; ++j) {
        const int f = 4 * (t + 1024 * j);
        s.a[j] = *(const float4*)(pl0 + f);
        s.b[j] = *(const float4*)(pl1 + f);
    }
    return s;
}

// z-combine + scatter into padded layout (interior cells only).
__device__ __forceinline__ void stage_store_pad(float* __restrict__ buf, const Stage& s,
                                                float wz0, float wz1, int t) {
#pragma unroll
    for (int j = 0; j < 4; ++j) {
        const int f = 4 * (t + 1024 * j);
        const int y = f >> 7, x = f & (WW - 1);
        float* p = &buf[(y + 1) * PSTRIDE + (x + 1)];
        p[0] = fmaf(wz0, s.a[j].x, wz1 * s.b[j].x);
        p[1] = fmaf(wz0, s.a[j].y, wz1 * s.b[j].y);
        p[2] = fmaf(wz0, s.a[j].z, wz1 * s.b[j].z);
        p[3] = fmaf(wz0, s.a[j].w, wz1 * s.b[j].w);
    }
}

// Bilinear gather from padded plane; P.z/P.w carry the +1 border bias.
// Clamp into [0,129.99]: OOB pixels read stored zeros (exact zero-padding).
// Thread covers 4 consecutive x at 4 k-positions -> float4 output stores.
__device__ __forceinline__ void gather_plane(const float* __restrict__ buf,
                                             const float4 P,
                                             float* __restrict__ outp,
                                             const float yf, const int xi) {
    const float cA = P.x, cB = P.y;
    const float xb = (float)(xi * 4);
    float ixp = fmaf(cA, xb, fmaf(-cB, yf, P.z));
    float iyp = fmaf(cB, xb, fmaf( cA, yf, P.w));
    const float dx32 = 32.0f * cA, dy32 = 32.0f * cB;
#pragma unroll
    for (int k = 0; k < 4; ++k) {
        float4 r;
        float ix = ixp, iy = iyp;
#pragma unroll
        for (int j = 0; j < 4; ++j) {
            const float xc  = fminf(fmaxf(ix, 0.0f), 129.99f);
            const float yc  = fminf(fmaxf(iy, 0.0f), 129.99f);
            const float x0f = floorf(xc), y0f = floorf(yc);
            const float fx  = xc - x0f,   fy  = yc - y0f;
            const int   a   = (int)y0f * PSTRIDE + (int)x0f;
            const float v00 = buf[a],           v01 = buf[a + 1];           // ds_read2
            const float v10 = buf[a + PSTRIDE], v11 = buf[a + PSTRIDE + 1]; // ds_read2
            const float h0  = fmaf(fx, v01 - v00, v00);
            const float h1  = fmaf(fx, v11 - v10, v10);
            (&r.x)[j] = fmaf(fy, h1 - h0, h0);
            ix += cA; iy += cB;
        }
        *(float4*)(outp + k * 32 + xi * 4) = r;   // global_store_dwordx4
        ixp += dx32; iyp += dy32;
    }
}

// ---------------------------------------------------------------------------
// One launch, 256 blocks x 1024 threads, NP=4 planes/block, LDS double buffer
// + 2-deep register prefetch: the vmcnt wait for plane i+1's loads always has
// plane i+2's 16 loads queued behind it, so the HBM pipe never drains.
// Plane 0 AND plane 1 loads issue before the params phase.
// ---------------------------------------------------------------------------
__global__ __launch_bounds__(1024, 4)
void adaat_fused_kernel(const float* __restrict__ fm,
                        const float* __restrict__ pc,
                        const float* __restrict__ W1, const float* __restrict__ b1,
                        const float* __restrict__ Ws, const float* __restrict__ bs,
                        const float* __restrict__ Wr, const float* __restrict__ br,
                        const float* __restrict__ Wt, const float* __restrict__ bt,
                        float* __restrict__ out) {
    __shared__ float  lds[2 * BUFSZ];   // 140.4 KiB padded double buffer
    __shared__ float  red[1024];        // GEMV reduce scratch
    __shared__ float  p_sh[PC];
    __shared__ float  sh_head[16];
    __shared__ float4 sh_par[NP];

    const int t   = threadIdx.x;
    const int bc0 = blockIdx.x * NP;    // NP | 256 so no batch straddle
    const int b   = bc0 >> 8;

    // block-uniform staging constants (scalarized)
    const float* base = fm + (size_t)b * (CH * PLANE);
    const float* pl0[NP]; const float* pl1[NP];
    float w0[NP], w1[NP];
#pragma unroll
    for (int i = 0; i < NP; ++i) {
        const int   c  = (bc0 + i) & (CH - 1);
        const float iz = (256.0f / 255.0f) * (float)c - 0.5f;
        const float zf = floorf(iz);
        const float fz = iz - zf;
        const int   z0 = (int)zf;
        w0[i]  = (z0 >= 0)     ? (1.0f - fz) : 0.0f;
        w1[i]  = (z0 + 1 < CH) ? fz          : 0.0f;
        pl0[i] = base + (size_t)max(z0, 0)          * PLANE;
        pl1[i] = base + (size_t)min(z0 + 1, CH - 1) * PLANE;
    }

    // ---- 1) planes 0 AND 1 in flight through the whole params phase ----
    Stage sA = stage_load(pl0[0], pl1[0], t);
    Stage sB = stage_load(pl0[1], pl1[1], t);

    // ---- 2) zero both padded buffers (borders must read 0.0f) ----
#pragma unroll
    for (int i = 0; i < 35; ++i) {
        const int idx = t + 1024 * i;
        if (idx < 2 * BUFSZ) lds[idx] = 0.0f;
    }

    // ---- 3) p = relu(pc @ W1 + b1), 4-way k-split ----
    {
        const int jj = t & 255, kk = t >> 8;
        const float* pcb = pc + b * PC + kk * 64;
        const float* w   = W1 + (kk * 64) * PC + jj;
        float acc = 0.0f;
#pragma unroll 8
        for (int i = 0; i < 64; ++i)
            acc = fmaf(pcb[i], w[i * PC], acc);
        red[t] = acc;
    }
    barrier_lds();
    if (t < 256)
        p_sh[t] = fmaxf(red[t] + red[256 + t] + red[512 + t] + red[768 + t] + b1[t], 0.0f);
    barrier_lds();   // p_sh visible; zeroing drained

    // ---- 4) head dots: wave wv -> channel q = wv>>2, head wv&3 ----
    const int wv = t >> 6, l = t & 63;
    {
        const int q  = wv >> 2;
        const int h  = wv & 3;
        const int cq = (bc0 + q) & (CH - 1);
        const float* wp; int stride;
        if      (h == 0) { wp = Ws + cq;                stride = PC;     }
        else if (h == 1) { wp = Wr + cq;                stride = PC;     }
        else             { wp = Wt + 2 * cq + (h == 3); stride = 2 * PC; }
        float dot = 0.0f;
#pragma unroll
        for (int m = 0; m < 4; ++m) {
            const int k = l + 64 * m;
            dot = fmaf(p_sh[k], wp[(size_t)k * stride], dot);
        }
#pragma unroll
        for (int off = 32; off >= 1; off >>= 1)
            dot += __shfl_xor(dot, off, 64);
        if (l == 0) sh_head[wv] = dot;
    }
    barrier_lds();

    // ---- 5) transcendentals -> fused padded-pixel-space constants ----
    if (t < NP) {
        const int cq = (bc0 + t) & (CH - 1);
        const float s2  = 2.0f / (1.0f + expf(-(sh_head[4 * t] + bs[cq])));
        const float ang = tanhf(sh_head[4 * t + 1] + br[cq]) * PI_F;
        float sa, ca;
        sincosf(ang, &sa, &ca);
        const float A  = s2 * ca, B = s2 * sa;
        const float Tx = tanhf(sh_head[4 * t + 2] + bt[2 * cq]);
        const float Ty = tanhf(sh_head[4 * t + 3] + bt[2 * cq + 1]);
        sh_par[t] = make_float4(A * (128.0f / 127.0f),
                                B * (128.0f / 127.0f),
                                64.0f * (Tx - A + B) + 64.5f,   // +1 border bias
                                64.0f * (Ty - A - B) + 64.5f);
    }

    // ---- 6) commit plane 0 (waits sA's vmcnt; sB + stores stay queued) ----
    stage_store_pad(&lds[0], sA, w0[0], w1[0], t);
    barrier_lds();   // sh_par + plane-0 stores visible

    const int   xi = l & 7;                 // 4 consecutive px, 4 k-slots
    const int   yj = wv * 8 + (l >> 3);
    const float yf = (float)yj;
    float* outb = out + (size_t)bc0 * PLANE + yj * WW;

    // ---- 7) pipeline: plane i gathers from buf[i&1] ----
    // i=0: prefetch plane2, gather0, commit plane1(sB) -> buf1
    sA = stage_load(pl0[2], pl1[2], t);
    gather_plane(&lds[0], sh_par[0], outb, yf, xi);
    stage_store_pad(&lds[BUFSZ], sB, w0[1], w1[1], t);
    barrier_lds();

    // i=1: prefetch plane3, gather1, commit plane2(sA) -> buf0
    sB = stage_load(pl0[3], pl1[3], t);
    gather_plane(&lds[BUFSZ], sh_par[1], outb + PLANE, yf, xi);
    stage_store_pad(&lds[0], sA, w0[2], w1[2], t);
    barrier_lds();

    // i=2: gather2, commit plane3(sB) -> buf1
    gather_plane(&lds[0], sh_par[2], outb + 2 * PLANE, yf, xi);
    stage_store_pad(&lds[BUFSZ], sB, w0[3], w1[3], t);
    barrier_lds();

    // i=3: final gather
    gather_plane(&lds[BUFSZ], sh_par[3], outb + 3 * PLANE, yf, xi);
}

// ---------------------------------------------------------------------------
extern "C" void kernel_launch(void* const* d_in, const int* in_sizes, int n_in,
                              void* d_out, int out_size, void* d_ws, size_t ws_size,
                              hipStream_t stream) {
    const float* feature_map = (const float*)d_in[0];  // [4,256,128,128]
    const float* para_code   = (const float*)d_in[1];  // [4,256]
    const float* W1 = (const float*)d_in[2];
    const float* b1 = (const float*)d_in[3];
    const float* Ws = (const float*)d_in[4];
    const float* bs = (const float*)d_in[5];
    const float* Wr = (const float*)d_in[6];
    const float* br = (const float*)d_in[7];
    const float* Wt = (const float*)d_in[8];
    const float* bt = (const float*)d_in[9];

    adaat_fused_kernel<<<BATCH * CH / NP, 1024, 0, stream>>>(
        feature_map, para_code, W1, b1, Ws, bs, Wr, br, Wt, bt, (float*)d_out);
}